// Round 6
// baseline (210.733 us; speedup 1.0000x reference)
//
#include <hip/hip_runtime.h>
#include <hip/hip_bf16.h>
#include <hip/hip_fp16.h>

#define JN 17
#define NTV 9

typedef __fp16 h2v __attribute__((ext_vector_type(2)));

__device__ __forceinline__ float lrelu(float x){ return fmaxf(x, 0.01f*x); }
__device__ __forceinline__ unsigned h2u(h2v h){ unsigned u; __builtin_memcpy(&u, &h, 4); return u; }
__device__ __forceinline__ h2v u2h(unsigned u){ h2v h; __builtin_memcpy(&h, &u, 4); return h; }
__device__ __forceinline__ unsigned pkrtz(float a, float b){ return h2u(__builtin_amdgcn_cvt_pkrtz(a,b)); }
__device__ __forceinline__ float fdot2(unsigned a, unsigned b, float c){
    return __builtin_amdgcn_fdot2(u2h(a), u2h(b), c, false);
}
__device__ __forceinline__ unsigned pkfma(unsigned a, unsigned b, unsigned c){
    h2v r = u2h(a)*u2h(b) + u2h(c);     // v_pk_fma_f16
    return h2u(r);
}

// ws header layout (u32 units), header occupies first 65536 bytes
#define OFF_PP    0        // 544 f32  : bud + positions @ Wud[32:64]
#define OFF_BQS   544      // 32 f32   : bq * (1/sqrt(32))
#define OFF_WUD   576      // 512 u32  : Wud[0:32] f16 pairs (p,h)
#define OFF_WQ    1088     // 512 u32  : Wq * isq pairs
#define OFF_WK    1600
#define OFF_WV    2112
#define OFF_WD1   2624
#define OFF_WD2   3136
#define OFF_WUP   3648     // 9248 u32 : Wup pairs (j,p,h)
#define HDR_BYTES 65536

// ---------------- prep: bitmask + pack weights to f16 pairs ------------------
__global__ __launch_bounds__(256,1)
void prep_kernel(const void* __restrict__ mraw, const float* __restrict__ pos,
                 const float* __restrict__ Wup,
                 const float* __restrict__ Wud, const float* __restrict__ bud,
                 const float* __restrict__ Wq,  const float* __restrict__ bq,
                 const float* __restrict__ Wk,  const float* __restrict__ Wv,
                 const float* __restrict__ Wd1, const float* __restrict__ Wd2,
                 unsigned* __restrict__ ws32, unsigned* __restrict__ bmask, int B)
{
    int g = blockIdx.x*256 + threadIdx.x;
    const float isq = 0.17677669529663687f;  // 1/sqrt(32)

    // mask mode detection (encodings mutually exclusive given 9-of-17 True)
    const unsigned* mw = (const unsigned*)mraw;
    bool f3f=false, nz=false;
    #pragma unroll
    for (int i=0;i<17;i++){
        unsigned w = mw[i];
        if ((w>>24) == 0x3Fu) f3f = true;
        if (w & 0xFFFFFF00u)  nz  = true;
    }
    int mode = f3f ? 2 : (nz ? 1 : 0);
    if (g < B){
        unsigned bm = 0; size_t base = (size_t)g*JN;
        if (mode == 0){
            const int* mi = (const int*)mraw;
            #pragma unroll
            for (int j=0;j<JN;j++) if (mi[base+j] != 0) bm |= (1u<<j);
        } else if (mode == 1){
            const unsigned char* mb = (const unsigned char*)mraw;
            #pragma unroll
            for (int j=0;j<JN;j++) if (mb[base+j] != 0) bm |= (1u<<j);
        } else {
            const float* mf = (const float*)mraw;
            #pragma unroll
            for (int j=0;j<JN;j++) if (mf[base+j] != 0.f) bm |= (1u<<j);
        }
        bmask[g] = bm;
    }
    if (g < 544){
        int j = g >> 5, h = g & 31;
        float acc = bud[h];
        #pragma unroll
        for (int c=0;c<32;c++) acc = fmaf(pos[j*32+c], Wud[(32+c)*32 + h], acc);
        ((float*)ws32)[OFF_PP + g] = acc;
    }
    if (g < 32) ((float*)ws32)[OFF_BQS + g] = bq[g]*isq;
    if (g < 512){
        int p = g >> 5, h = g & 31;
        int c0 = 2*p, c1 = 2*p+1;
        ws32[OFF_WUD + g] = pkrtz(Wud[c0*32+h],      Wud[c1*32+h]);
        ws32[OFF_WQ  + g] = pkrtz(Wq [c0*32+h]*isq,  Wq [c1*32+h]*isq);
        ws32[OFF_WK  + g] = pkrtz(Wk [c0*32+h],      Wk [c1*32+h]);
        ws32[OFF_WV  + g] = pkrtz(Wv [c0*32+h],      Wv [c1*32+h]);
        ws32[OFF_WD1 + g] = pkrtz(Wd1[c0*32+h],      Wd1[c1*32+h]);
        ws32[OFF_WD2 + g] = pkrtz(Wd2[c0*32+h],      Wd2[c1*32+h]);
    }
    if (g < 9248){
        int h = g & 31, p = (g >> 5) % 17, j = g / (32*17);
        ws32[OFF_WUP + g] = pkrtz(Wup[(2*p)*544 + j*32 + h], Wup[(2*p+1)*544 + j*32 + h]);
    }
}

// ---------------- pass 1: one lane per (2 samples, joint); j = blockIdx.y ----
// Two samples per lane: each scalar weight feeds two independent dot2 chains.
__global__ __launch_bounds__(256,4)
void pass1_kernel(const float* __restrict__ x, const unsigned* __restrict__ bmask,
                  const unsigned* __restrict__ ws32,
                  const float* __restrict__ bup,
                  const float* __restrict__ bk, const float* __restrict__ bv,
                  unsigned* __restrict__ ku, unsigned* __restrict__ vu,
                  unsigned* __restrict__ uuo, unsigned* __restrict__ upo,
                  int start, int n, long cap)
{
    int li = blockIdx.x*256 + threadIdx.x;
    int ss0 = 2*li, ss1 = 2*li+1;            // chunk-local sample indices
    if (ss0 >= n) return;
    const bool has1 = (ss1 < n);
    const int s0 = start + ss0;
    const int s1 = start + (has1 ? ss1 : ss0);
    const int j = blockIdx.y;

    unsigned xp0[17], xp1[17];
    {
        const float2* xf0 = (const float2*)(x + (size_t)s0*34);
        const float2* xf1 = (const float2*)(x + (size_t)s1*34);
        #pragma unroll
        for (int i=0;i<17;i++){
            float2 t0 = xf0[i], t1 = xf1[i];
            xp0[i] = pkrtz(t0.x, t0.y);
            xp1[i] = pkrtz(t1.x, t1.y);
        }
    }
    const unsigned bm0 = bmask[s0], bm1 = bmask[s1];
    const bool occ0 = !((bm0>>j)&1u);
    const bool occ1 = has1 && !((bm1>>j)&1u);
    const int rk0 = __popc((~bm0) & ((1u<<j)-1u));
    const int rk1 = __popc((~bm1) & ((1u<<j)-1u));

    const unsigned* wup = ws32 + OFF_WUP + (size_t)j*17*32;
    const float*    pp  = (const float*)ws32 + OFF_PP + j*32;
    const unsigned* wud = ws32 + OFF_WUD;
    const unsigned* wk  = ws32 + OFF_WK;
    const unsigned* wv  = ws32 + OFF_WV;

    // up = leaky(x @ Wup_j + bup_j)
    float up0[32], up1[32];
    #pragma unroll
    for (int h=0;h<32;h++){ float b = bup[j*32+h]; up0[h]=b; up1[h]=b; }
    #pragma unroll
    for (int p=0;p<17;p++){
        unsigned a0 = xp0[p], a1 = xp1[p];
        #pragma unroll
        for (int h=0;h<32;h++){
            unsigned w = wup[p*32+h];
            up0[h] = fdot2(a0, w, up0[h]);
            up1[h] = fdot2(a1, w, up1[h]);
        }
    }
    unsigned upk0[16], upk1[16];
    #pragma unroll
    for (int p=0;p<16;p++){
        upk0[p] = pkrtz(lrelu(up0[2*p]), lrelu(up0[2*p+1]));
        upk1[p] = pkrtz(lrelu(up1[2*p]), lrelu(up1[2*p+1]));
    }

    if (occ0){
        uint4* d = (uint4*)(upo + ((size_t)ss0*8 + rk0)*16);
        d[0] = make_uint4(upk0[0],upk0[1],upk0[2],upk0[3]);
        d[1] = make_uint4(upk0[4],upk0[5],upk0[6],upk0[7]);
        d[2] = make_uint4(upk0[8],upk0[9],upk0[10],upk0[11]);
        d[3] = make_uint4(upk0[12],upk0[13],upk0[14],upk0[15]);
    }
    if (occ1){
        uint4* d = (uint4*)(upo + ((size_t)ss1*8 + rk1)*16);
        d[0] = make_uint4(upk1[0],upk1[1],upk1[2],upk1[3]);
        d[1] = make_uint4(upk1[4],upk1[5],upk1[6],upk1[7]);
        d[2] = make_uint4(upk1[8],upk1[9],upk1[10],upk1[11]);
        d[3] = make_uint4(upk1[12],upk1[13],upk1[14],upk1[15]);
    }

    // uu = leaky(pp_j + up @ Wud0)
    float uu0[32], uu1[32];
    #pragma unroll
    for (int h=0;h<32;h++){ float b = pp[h]; uu0[h]=b; uu1[h]=b; }
    #pragma unroll
    for (int p=0;p<16;p++){
        unsigned a0 = upk0[p], a1 = upk1[p];
        #pragma unroll
        for (int h=0;h<32;h++){
            unsigned w = wud[p*32+h];
            uu0[h] = fdot2(a0, w, uu0[h]);
            uu1[h] = fdot2(a1, w, uu1[h]);
        }
    }
    unsigned uupk0[16], uupk1[16];
    #pragma unroll
    for (int p=0;p<16;p++){
        uupk0[p] = pkrtz(lrelu(uu0[2*p]), lrelu(uu0[2*p+1]));
        uupk1[p] = pkrtz(lrelu(uu1[2*p]), lrelu(uu1[2*p+1]));
    }

    if (occ0){
        uint4* d = (uint4*)(uuo + ((size_t)ss0*8 + rk0)*16);
        d[0] = make_uint4(uupk0[0],uupk0[1],uupk0[2],uupk0[3]);
        d[1] = make_uint4(uupk0[4],uupk0[5],uupk0[6],uupk0[7]);
        d[2] = make_uint4(uupk0[8],uupk0[9],uupk0[10],uupk0[11]);
        d[3] = make_uint4(uupk0[12],uupk0[13],uupk0[14],uupk0[15]);
    }
    if (occ1){
        uint4* d = (uint4*)(uuo + ((size_t)ss1*8 + rk1)*16);
        d[0] = make_uint4(uupk1[0],uupk1[1],uupk1[2],uupk1[3]);
        d[1] = make_uint4(uupk1[4],uupk1[5],uupk1[6],uupk1[7]);
        d[2] = make_uint4(uupk1[8],uupk1[9],uupk1[10],uupk1[11]);
        d[3] = make_uint4(uupk1[12],uupk1[13],uupk1[14],uupk1[15]);
    }

    // k rows
    {
        float a0c[32], a1c[32];
        #pragma unroll
        for (int h=0;h<32;h++){ float b = bk[h]; a0c[h]=b; a1c[h]=b; }
        #pragma unroll
        for (int p=0;p<16;p++){
            unsigned a0 = uupk0[p], a1 = uupk1[p];
            #pragma unroll
            for (int h=0;h<32;h++){
                unsigned w = wk[p*32+h];
                a0c[h] = fdot2(a0, w, a0c[h]);
                a1c[h] = fdot2(a1, w, a1c[h]);
            }
        }
        unsigned t0[16], t1[16];
        #pragma unroll
        for (int p=0;p<16;p++){ t0[p]=pkrtz(a0c[2*p],a0c[2*p+1]); t1[p]=pkrtz(a1c[2*p],a1c[2*p+1]); }
        uint4* d0 = (uint4*)(ku + ((size_t)j*cap + ss0)*16);
        d0[0] = make_uint4(t0[0],t0[1],t0[2],t0[3]);
        d0[1] = make_uint4(t0[4],t0[5],t0[6],t0[7]);
        d0[2] = make_uint4(t0[8],t0[9],t0[10],t0[11]);
        d0[3] = make_uint4(t0[12],t0[13],t0[14],t0[15]);
        if (has1){
            uint4* d1 = (uint4*)(ku + ((size_t)j*cap + ss1)*16);
            d1[0] = make_uint4(t1[0],t1[1],t1[2],t1[3]);
            d1[1] = make_uint4(t1[4],t1[5],t1[6],t1[7]);
            d1[2] = make_uint4(t1[8],t1[9],t1[10],t1[11]);
            d1[3] = make_uint4(t1[12],t1[13],t1[14],t1[15]);
        }
    }
    // v rows
    {
        float a0c[32], a1c[32];
        #pragma unroll
        for (int h=0;h<32;h++){ float b = bv[h]; a0c[h]=b; a1c[h]=b; }
        #pragma unroll
        for (int p=0;p<16;p++){
            unsigned a0 = uupk0[p], a1 = uupk1[p];
            #pragma unroll
            for (int h=0;h<32;h++){
                unsigned w = wv[p*32+h];
                a0c[h] = fdot2(a0, w, a0c[h]);
                a1c[h] = fdot2(a1, w, a1c[h]);
            }
        }
        unsigned t0[16], t1[16];
        #pragma unroll
        for (int p=0;p<16;p++){ t0[p]=pkrtz(a0c[2*p],a0c[2*p+1]); t1[p]=pkrtz(a1c[2*p],a1c[2*p+1]); }
        uint4* d0 = (uint4*)(vu + ((size_t)j*cap + ss0)*16);
        d0[0] = make_uint4(t0[0],t0[1],t0[2],t0[3]);
        d0[1] = make_uint4(t0[4],t0[5],t0[6],t0[7]);
        d0[2] = make_uint4(t0[8],t0[9],t0[10],t0[11]);
        d0[3] = make_uint4(t0[12],t0[13],t0[14],t0[15]);
        if (has1){
            uint4* d1 = (uint4*)(vu + ((size_t)j*cap + ss1)*16);
            d1[0] = make_uint4(t1[0],t1[1],t1[2],t1[3]);
            d1[1] = make_uint4(t1[4],t1[5],t1[6],t1[7]);
            d1[2] = make_uint4(t1[8],t1[9],t1[10],t1[11]);
            d1[3] = make_uint4(t1[12],t1[13],t1[14],t1[15]);
        }
    }
}

// ---------------- pass 2: one lane per (sample, 2 queries) -------------------
// Queries qp and qp+4 of the same sample: k/v rows loaded once, used twice.
__global__ __launch_bounds__(256,4)
void pass2_kernel(const unsigned* __restrict__ ku, const unsigned* __restrict__ vu,
                  const unsigned* __restrict__ uuo, const unsigned* __restrict__ upo,
                  const unsigned* __restrict__ ws32,
                  const float* __restrict__ bd1, const float* __restrict__ bd2,
                  const float* __restrict__ Ws, const float* __restrict__ bs,
                  float* __restrict__ out, int start, int n, long cap)
{
    int g = blockIdx.x*256 + threadIdx.x;
    if (g >= n*4) return;
    int sl = g >> 2, qp = g & 3;
    int q0 = qp, q1 = qp + 4;

    const unsigned* wq  = ws32 + OFF_WQ;
    const unsigned* wd1 = ws32 + OFF_WD1;
    const unsigned* wd2 = ws32 + OFF_WD2;
    const float*    bqs = (const float*)ws32 + OFF_BQS;

    unsigned uw0[16], uw1[16];
    {
        const uint4* p4 = (const uint4*)(uuo + ((size_t)sl*8 + q0)*16);
        uint4 a = p4[0], b = p4[1], c = p4[2], d = p4[3];
        uw0[0]=a.x; uw0[1]=a.y; uw0[2]=a.z; uw0[3]=a.w;
        uw0[4]=b.x; uw0[5]=b.y; uw0[6]=b.z; uw0[7]=b.w;
        uw0[8]=c.x; uw0[9]=c.y; uw0[10]=c.z; uw0[11]=c.w;
        uw0[12]=d.x; uw0[13]=d.y; uw0[14]=d.z; uw0[15]=d.w;
    }
    {
        const uint4* p4 = (const uint4*)(uuo + ((size_t)sl*8 + q1)*16);
        uint4 a = p4[0], b = p4[1], c = p4[2], d = p4[3];
        uw1[0]=a.x; uw1[1]=a.y; uw1[2]=a.z; uw1[3]=a.w;
        uw1[4]=b.x; uw1[5]=b.y; uw1[6]=b.z; uw1[7]=b.w;
        uw1[8]=c.x; uw1[9]=c.y; uw1[10]=c.z; uw1[11]=c.w;
        uw1[12]=d.x; uw1[13]=d.y; uw1[14]=d.z; uw1[15]=d.w;
    }

    float qa0[32], qa1[32];
    #pragma unroll
    for (int h=0;h<32;h++){ float b = bqs[h]; qa0[h]=b; qa1[h]=b; }
    #pragma unroll
    for (int p=0;p<16;p++){
        unsigned a0 = uw0[p], a1 = uw1[p];
        #pragma unroll
        for (int h=0;h<32;h++){
            unsigned w = wq[p*32+h];
            qa0[h] = fdot2(a0, w, qa0[h]);
            qa1[h] = fdot2(a1, w, qa1[h]);
        }
    }
    unsigned qpk0[16], qpk1[16];
    #pragma unroll
    for (int p=0;p<16;p++){ qpk0[p]=pkrtz(qa0[2*p],qa0[2*p+1]); qpk1[p]=pkrtz(qa1[2*p],qa1[2*p+1]); }

    // scores vs all 17 keys; k rows shared across both queries
    float sc0[JN], sc1[JN];
    #pragma unroll
    for (int kj=0;kj<JN;kj++){
        const uint4* kp = (const uint4*)(ku + ((size_t)kj*cap + sl)*16);
        uint4 a = kp[0], b = kp[1], c = kp[2], d = kp[3];
        unsigned kw[16] = {a.x,a.y,a.z,a.w,b.x,b.y,b.z,b.w,c.x,c.y,c.z,c.w,d.x,d.y,d.z,d.w};
        float s00=0.f, s01=0.f, s10=0.f, s11=0.f;
        #pragma unroll
        for (int p=0;p<16;p+=2){
            s00 = fdot2(qpk0[p],   kw[p],   s00);
            s01 = fdot2(qpk0[p+1], kw[p+1], s01);
            s10 = fdot2(qpk1[p],   kw[p],   s10);
            s11 = fdot2(qpk1[p+1], kw[p+1], s11);
        }
        sc0[kj] = s00 + s01; sc1[kj] = s10 + s11;
    }
    float m0 = sc0[0], m1 = sc1[0];
    #pragma unroll
    for (int kj=1;kj<JN;kj++){ m0 = fmaxf(m0, sc0[kj]); m1 = fmaxf(m1, sc1[kj]); }
    float e0[JN], e1[JN]; float sum0 = 0.f, sum1 = 0.f;
    #pragma unroll
    for (int kj=0;kj<JN;kj++){
        e0[kj] = __expf(sc0[kj]-m0); sum0 += e0[kj];
        e1[kj] = __expf(sc1[kj]-m1); sum1 += e1[kj];
    }
    float ri0 = 1.0f/sum0, ri1 = 1.0f/sum1;

    // o = att @ v (f16 pair accumulate); v rows shared
    unsigned o0[16], o1[16];
    #pragma unroll
    for (int p=0;p<16;p++){ o0[p]=0u; o1[p]=0u; }
    #pragma unroll
    for (int kj=0;kj<JN;kj++){
        float w0 = e0[kj]*ri0, w1 = e1[kj]*ri1;
        unsigned w20 = pkrtz(w0, w0), w21 = pkrtz(w1, w1);
        const uint4* vp = (const uint4*)(vu + ((size_t)kj*cap + sl)*16);
        uint4 a = vp[0], b = vp[1], c = vp[2], d = vp[3];
        unsigned vw[16] = {a.x,a.y,a.z,a.w,b.x,b.y,b.z,b.w,c.x,c.y,c.z,c.w,d.x,d.y,d.z,d.w};
        #pragma unroll
        for (int p=0;p<16;p++){ o0[p] = pkfma(w20, vw[p], o0[p]); o1[p] = pkfma(w21, vw[p], o1[p]); }
    }

    // d1 = leaky(o @ Wd1 + bd1)
    float t0[32], t1[32];
    #pragma unroll
    for (int h=0;h<32;h++){ float b = bd1[h]; t0[h]=b; t1[h]=b; }
    #pragma unroll
    for (int p=0;p<16;p++){
        unsigned a0 = o0[p], a1 = o1[p];
        #pragma unroll
        for (int h=0;h<32;h++){
            unsigned w = wd1[p*32+h];
            t0[h] = fdot2(a0, w, t0[h]);
            t1[h] = fdot2(a1, w, t1[h]);
        }
    }
    unsigned tp0[16], tp1[16];
    #pragma unroll
    for (int p=0;p<16;p++){
        tp0[p] = pkrtz(lrelu(t0[2*p]), lrelu(t0[2*p+1]));
        tp1[p] = pkrtz(lrelu(t1[2*p]), lrelu(t1[2*p+1]));
    }

    // d2 + residual
    float z0[32], z1[32];
    {
        const uint4* p4 = (const uint4*)(upo + ((size_t)sl*8 + q0)*16);
        uint4 a = p4[0], b = p4[1], c = p4[2], d = p4[3];
        unsigned pw[16] = {a.x,a.y,a.z,a.w,b.x,b.y,b.z,b.w,c.x,c.y,c.z,c.w,d.x,d.y,d.z,d.w};
        #pragma unroll
        for (int p=0;p<16;p++){
            h2v r = u2h(pw[p]);
            z0[2*p] = bd2[2*p] + (float)r.x; z0[2*p+1] = bd2[2*p+1] + (float)r.y;
        }
    }
    {
        const uint4* p4 = (const uint4*)(upo + ((size_t)sl*8 + q1)*16);
        uint4 a = p4[0], b = p4[1], c = p4[2], d = p4[3];
        unsigned pw[16] = {a.x,a.y,a.z,a.w,b.x,b.y,b.z,b.w,c.x,c.y,c.z,c.w,d.x,d.y,d.z,d.w};
        #pragma unroll
        for (int p=0;p<16;p++){
            h2v r = u2h(pw[p]);
            z1[2*p] = bd2[2*p] + (float)r.x; z1[2*p+1] = bd2[2*p+1] + (float)r.y;
        }
    }
    #pragma unroll
    for (int p=0;p<16;p++){
        unsigned a0 = tp0[p], a1 = tp1[p];
        #pragma unroll
        for (int h=0;h<32;h++){
            unsigned w = wd2[p*32+h];
            z0[h] = fdot2(a0, w, z0[h]);
            z1[h] = fdot2(a1, w, z1[h]);
        }
    }

    // sigmoid(z @ Ws + bs)
    float y00=0.f, y01=0.f, y10=0.f, y11=0.f;
    #pragma unroll
    for (int h=0;h<32;h+=2){
        y00 = fmaf(z0[h], Ws[h], y00); y01 = fmaf(z0[h+1], Ws[h+1], y01);
        y10 = fmaf(z1[h], Ws[h], y10); y11 = fmaf(z1[h+1], Ws[h+1], y11);
    }
    float yb = bs[0];
    float ya = y00 + y01 + yb;
    float yc = y10 + y11 + yb;
    size_t ob = ((size_t)(start + sl))*8;
    out[ob + q0] = 1.0f/(1.0f + __expf(-ya));
    out[ob + q1] = 1.0f/(1.0f + __expf(-yc));
}

extern "C" void kernel_launch(void* const* d_in, const int* in_sizes, int n_in,
                              void* d_out, int out_size, void* d_ws, size_t ws_size,
                              hipStream_t stream) {
    (void)n_in; (void)out_size;
    const float* x   = (const float*)d_in[0];
    const void*  m   = d_in[1];
    const float* pos = (const float*)d_in[2];
    const float* Wup = (const float*)d_in[3];  const float* bup = (const float*)d_in[4];
    const float* Wud = (const float*)d_in[5];  const float* bud = (const float*)d_in[6];
    const float* Wq  = (const float*)d_in[7];  const float* bq  = (const float*)d_in[8];
    const float* Wk  = (const float*)d_in[9];  const float* bk  = (const float*)d_in[10];
    const float* Wv  = (const float*)d_in[11]; const float* bv  = (const float*)d_in[12];
    const float* Wd1 = (const float*)d_in[13]; const float* bd1 = (const float*)d_in[14];
    const float* Wd2 = (const float*)d_in[15]; const float* bd2 = (const float*)d_in[16];
    const float* Ws  = (const float*)d_in[17]; const float* bs  = (const float*)d_in[18];
    float* out = (float*)d_out;
    int B = in_sizes[0] / (JN*2);

    unsigned char* wsb = (unsigned char*)d_ws;
    unsigned* ws32  = (unsigned*)wsb;                           // 64 KB header
    unsigned* bmask = (unsigned*)(wsb + HDR_BYTES);             // B u32
    size_t data_off = (HDR_BYTES + (size_t)B*4 + 255) & ~(size_t)255;
    // per-sample ws: k (17*16) + v (17*16) + uuo 128 + upo 128 = 800 u32 = 3200 B
    long cap = 0;
    if (ws_size > data_off) cap = (long)((ws_size - data_off) / 3200);
    cap = (cap/64)*64;
    if (cap <= 0) return;
    if (cap > B) cap = (long)B;
    unsigned* ku  = (unsigned*)(wsb + data_off);
    unsigned* vu  = ku  + (size_t)cap*272;
    unsigned* uuo = ku  + (size_t)cap*544;
    unsigned* upo = ku  + (size_t)cap*672;

    prep_kernel<<<(B+255)/256, 256, 0, stream>>>(m, pos, Wup, Wud, bud, Wq, bq,
                                                 Wk, Wv, Wd1, Wd2, ws32, bmask, B);
    for (long start = 0; start < B; start += cap){
        int n = (int)((B - start < cap) ? (B - start) : cap);
        int npair = (n + 1) / 2;
        dim3 g1((npair + 255)/256, JN);
        pass1_kernel<<<g1, 256, 0, stream>>>(x, bmask, ws32, bup, bk, bv,
                                             ku, vu, uuo, upo, (int)start, n, cap);
        pass2_kernel<<<(n*4 + 255)/256, 256, 0, stream>>>(ku, vu, uuo, upo, ws32,
                                                          bd1, bd2, Ws, bs,
                                                          out, (int)start, n, cap);
    }
}

// Round 7
// 158.068 us; speedup vs baseline: 1.3332x; 1.3332x over previous
//
#include <hip/hip_runtime.h>
#include <hip/hip_bf16.h>
#include <hip/hip_fp16.h>

#define JN 17
#define NTV 9

typedef __fp16 h2v __attribute__((ext_vector_type(2)));

__device__ __forceinline__ float lrelu(float x){ return fmaxf(x, 0.01f*x); }
__device__ __forceinline__ unsigned h2u(h2v h){ unsigned u; __builtin_memcpy(&u, &h, 4); return u; }
__device__ __forceinline__ h2v u2h(unsigned u){ h2v h; __builtin_memcpy(&h, &u, 4); return h; }
__device__ __forceinline__ unsigned pkrtz(float a, float b){ return h2u(__builtin_amdgcn_cvt_pkrtz(a,b)); }
__device__ __forceinline__ float fdot2(unsigned a, unsigned b, float c){
    return __builtin_amdgcn_fdot2(u2h(a), u2h(b), c, false);
}
__device__ __forceinline__ unsigned pkfma(unsigned a, unsigned b, unsigned c){
    h2v r = u2h(a)*u2h(b) + u2h(c);     // v_pk_fma_f16
    return h2u(r);
}

// ws header layout (u32 units), header occupies first 65536 bytes
#define OFF_PP    0        // 544 f32  : bud + positions @ Wud[32:64]
#define OFF_BQS   544      // 32 f32   : bq * (1/sqrt(32))
#define OFF_WUD   576      // 512 u32  : Wud[0:32] f16 pairs (p,h)
#define OFF_WQ    1088     // 512 u32  : Wq * isq pairs
#define OFF_WK    1600
#define OFF_WV    2112
#define OFF_WD1   2624
#define OFF_WD2   3136
#define OFF_WUP   3648     // 9248 u32 : Wup pairs (j,p,h)
#define HDR_BYTES 65536

// ---------------- prep: bitmask + pack weights to f16 pairs ------------------
__global__ __launch_bounds__(256,1)
void prep_kernel(const void* __restrict__ mraw, const float* __restrict__ pos,
                 const float* __restrict__ Wup,
                 const float* __restrict__ Wud, const float* __restrict__ bud,
                 const float* __restrict__ Wq,  const float* __restrict__ bq,
                 const float* __restrict__ Wk,  const float* __restrict__ Wv,
                 const float* __restrict__ Wd1, const float* __restrict__ Wd2,
                 unsigned* __restrict__ ws32, unsigned* __restrict__ bmask, int B)
{
    int g = blockIdx.x*256 + threadIdx.x;
    const float isq = 0.17677669529663687f;  // 1/sqrt(32)

    // mask mode detection (encodings mutually exclusive given 9-of-17 True)
    const unsigned* mw = (const unsigned*)mraw;
    bool f3f=false, nz=false;
    #pragma unroll
    for (int i=0;i<17;i++){
        unsigned w = mw[i];
        if ((w>>24) == 0x3Fu) f3f = true;
        if (w & 0xFFFFFF00u)  nz  = true;
    }
    int mode = f3f ? 2 : (nz ? 1 : 0);
    if (g < B){
        unsigned bm = 0; size_t base = (size_t)g*JN;
        if (mode == 0){
            const int* mi = (const int*)mraw;
            #pragma unroll
            for (int j=0;j<JN;j++) if (mi[base+j] != 0) bm |= (1u<<j);
        } else if (mode == 1){
            const unsigned char* mb = (const unsigned char*)mraw;
            #pragma unroll
            for (int j=0;j<JN;j++) if (mb[base+j] != 0) bm |= (1u<<j);
        } else {
            const float* mf = (const float*)mraw;
            #pragma unroll
            for (int j=0;j<JN;j++) if (mf[base+j] != 0.f) bm |= (1u<<j);
        }
        bmask[g] = bm;
    }
    if (g < 544){
        int j = g >> 5, h = g & 31;
        float acc = bud[h];
        #pragma unroll
        for (int c=0;c<32;c++) acc = fmaf(pos[j*32+c], Wud[(32+c)*32 + h], acc);
        ((float*)ws32)[OFF_PP + g] = acc;
    }
    if (g < 32) ((float*)ws32)[OFF_BQS + g] = bq[g]*isq;
    if (g < 512){
        int p = g >> 5, h = g & 31;
        int c0 = 2*p, c1 = 2*p+1;
        ws32[OFF_WUD + g] = pkrtz(Wud[c0*32+h],      Wud[c1*32+h]);
        ws32[OFF_WQ  + g] = pkrtz(Wq [c0*32+h]*isq,  Wq [c1*32+h]*isq);
        ws32[OFF_WK  + g] = pkrtz(Wk [c0*32+h],      Wk [c1*32+h]);
        ws32[OFF_WV  + g] = pkrtz(Wv [c0*32+h],      Wv [c1*32+h]);
        ws32[OFF_WD1 + g] = pkrtz(Wd1[c0*32+h],      Wd1[c1*32+h]);
        ws32[OFF_WD2 + g] = pkrtz(Wd2[c0*32+h],      Wd2[c1*32+h]);
    }
    if (g < 9248){
        int h = g & 31, p = (g >> 5) % 17, j = g / (32*17);
        ws32[OFF_WUP + g] = pkrtz(Wup[(2*p)*544 + j*32 + h], Wup[(2*p+1)*544 + j*32 + h]);
    }
}

// ---------------- pass 1: one lane per (sample, joint); j = blockIdx.y -------
// (round-5 structure: single sample per lane, VGPR~28, measured 105 us)
__global__ __launch_bounds__(256,4)
void pass1_kernel(const float* __restrict__ x, const unsigned* __restrict__ bmask,
                  const unsigned* __restrict__ ws32,
                  const float* __restrict__ bup,
                  const float* __restrict__ bk, const float* __restrict__ bv,
                  unsigned* __restrict__ ku, unsigned* __restrict__ vu,
                  unsigned* __restrict__ uuo, unsigned* __restrict__ upo,
                  int start, int n, long cap)
{
    int li = blockIdx.x*256 + threadIdx.x;
    if (li >= n) return;
    const int j = blockIdx.y;
    const int s = start + li;

    // pack x to 17 f16 pairs
    unsigned xp[17];
    const float2* xf = (const float2*)(x + (size_t)s*34);
    #pragma unroll
    for (int i=0;i<17;i++){ float2 t = xf[i]; xp[i] = pkrtz(t.x, t.y); }
    const unsigned bm = bmask[s];
    const bool occ = !((bm>>j)&1u);
    const int rk = __popc((~bm) & ((1u<<j)-1u));

    const unsigned* wup = ws32 + OFF_WUP + (size_t)j*17*32;
    const float*    pp  = (const float*)ws32 + OFF_PP + j*32;
    const unsigned* wud = ws32 + OFF_WUD;
    const unsigned* wk  = ws32 + OFF_WK;
    const unsigned* wv  = ws32 + OFF_WV;

    // up = leaky(x @ Wup_j + bup_j)
    float up[32];
    #pragma unroll
    for (int h=0;h<32;h++) up[h] = bup[j*32+h];
    #pragma unroll
    for (int p=0;p<17;p++){
        unsigned a = xp[p];
        #pragma unroll
        for (int h=0;h<32;h++) up[h] = fdot2(a, wup[p*32+h], up[h]);
    }
    unsigned upk[16];
    #pragma unroll
    for (int p=0;p<16;p++){ upk[p] = pkrtz(lrelu(up[2*p]), lrelu(up[2*p+1])); }

    if (occ){   // residual row (x2) for pass 2
        uint4* d = (uint4*)(upo + ((size_t)li*8 + rk)*16);
        d[0] = make_uint4(upk[0],upk[1],upk[2],upk[3]);
        d[1] = make_uint4(upk[4],upk[5],upk[6],upk[7]);
        d[2] = make_uint4(upk[8],upk[9],upk[10],upk[11]);
        d[3] = make_uint4(upk[12],upk[13],upk[14],upk[15]);
    }

    // uu = leaky(pp_j + up @ Wud0)
    float uu[32];
    #pragma unroll
    for (int h=0;h<32;h++) uu[h] = pp[h];
    #pragma unroll
    for (int p=0;p<16;p++){
        unsigned a = upk[p];
        #pragma unroll
        for (int h=0;h<32;h++) uu[h] = fdot2(a, wud[p*32+h], uu[h]);
    }
    unsigned uupk[16];
    #pragma unroll
    for (int p=0;p<16;p++){ uupk[p] = pkrtz(lrelu(uu[2*p]), lrelu(uu[2*p+1])); }

    if (occ){
        uint4* d = (uint4*)(uuo + ((size_t)li*8 + rk)*16);
        d[0] = make_uint4(uupk[0],uupk[1],uupk[2],uupk[3]);
        d[1] = make_uint4(uupk[4],uupk[5],uupk[6],uupk[7]);
        d[2] = make_uint4(uupk[8],uupk[9],uupk[10],uupk[11]);
        d[3] = make_uint4(uupk[12],uupk[13],uupk[14],uupk[15]);
    }

    // k row
    {
        float acc[32];
        #pragma unroll
        for (int h=0;h<32;h++) acc[h] = bk[h];
        #pragma unroll
        for (int p=0;p<16;p++){
            unsigned a = uupk[p];
            #pragma unroll
            for (int h=0;h<32;h++) acc[h] = fdot2(a, wk[p*32+h], acc[h]);
        }
        unsigned t[16];
        #pragma unroll
        for (int p=0;p<16;p++) t[p] = pkrtz(acc[2*p], acc[2*p+1]);
        uint4* d = (uint4*)(ku + ((size_t)j*cap + li)*16);
        d[0] = make_uint4(t[0],t[1],t[2],t[3]);
        d[1] = make_uint4(t[4],t[5],t[6],t[7]);
        d[2] = make_uint4(t[8],t[9],t[10],t[11]);
        d[3] = make_uint4(t[12],t[13],t[14],t[15]);
    }
    // v row
    {
        float acc[32];
        #pragma unroll
        for (int h=0;h<32;h++) acc[h] = bv[h];
        #pragma unroll
        for (int p=0;p<16;p++){
            unsigned a = uupk[p];
            #pragma unroll
            for (int h=0;h<32;h++) acc[h] = fdot2(a, wv[p*32+h], acc[h]);
        }
        unsigned t[16];
        #pragma unroll
        for (int p=0;p<16;p++) t[p] = pkrtz(acc[2*p], acc[2*p+1]);
        uint4* d = (uint4*)(vu + ((size_t)j*cap + li)*16);
        d[0] = make_uint4(t[0],t[1],t[2],t[3]);
        d[1] = make_uint4(t[4],t[5],t[6],t[7]);
        d[2] = make_uint4(t[8],t[9],t[10],t[11]);
        d[3] = make_uint4(t[12],t[13],t[14],t[15]);
    }
}

// ---------------- pass 2: one lane per (sample, 2 queries) -------------------
// Queries qp and qp+4 of the same sample: k/v rows loaded once, used twice.
// (round-6 structure, measured ~40 us)
__global__ __launch_bounds__(256,4)
void pass2_kernel(const unsigned* __restrict__ ku, const unsigned* __restrict__ vu,
                  const unsigned* __restrict__ uuo, const unsigned* __restrict__ upo,
                  const unsigned* __restrict__ ws32,
                  const float* __restrict__ bd1, const float* __restrict__ bd2,
                  const float* __restrict__ Ws, const float* __restrict__ bs,
                  float* __restrict__ out, int start, int n, long cap)
{
    int g = blockIdx.x*256 + threadIdx.x;
    if (g >= n*4) return;
    int sl = g >> 2, qp = g & 3;
    int q0 = qp, q1 = qp + 4;

    const unsigned* wq  = ws32 + OFF_WQ;
    const unsigned* wd1 = ws32 + OFF_WD1;
    const unsigned* wd2 = ws32 + OFF_WD2;
    const float*    bqs = (const float*)ws32 + OFF_BQS;

    unsigned uw0[16], uw1[16];
    {
        const uint4* p4 = (const uint4*)(uuo + ((size_t)sl*8 + q0)*16);
        uint4 a = p4[0], b = p4[1], c = p4[2], d = p4[3];
        uw0[0]=a.x; uw0[1]=a.y; uw0[2]=a.z; uw0[3]=a.w;
        uw0[4]=b.x; uw0[5]=b.y; uw0[6]=b.z; uw0[7]=b.w;
        uw0[8]=c.x; uw0[9]=c.y; uw0[10]=c.z; uw0[11]=c.w;
        uw0[12]=d.x; uw0[13]=d.y; uw0[14]=d.z; uw0[15]=d.w;
    }
    {
        const uint4* p4 = (const uint4*)(uuo + ((size_t)sl*8 + q1)*16);
        uint4 a = p4[0], b = p4[1], c = p4[2], d = p4[3];
        uw1[0]=a.x; uw1[1]=a.y; uw1[2]=a.z; uw1[3]=a.w;
        uw1[4]=b.x; uw1[5]=b.y; uw1[6]=b.z; uw1[7]=b.w;
        uw1[8]=c.x; uw1[9]=c.y; uw1[10]=c.z; uw1[11]=c.w;
        uw1[12]=d.x; uw1[13]=d.y; uw1[14]=d.z; uw1[15]=d.w;
    }

    float qa0[32], qa1[32];
    #pragma unroll
    for (int h=0;h<32;h++){ float b = bqs[h]; qa0[h]=b; qa1[h]=b; }
    #pragma unroll
    for (int p=0;p<16;p++){
        unsigned a0 = uw0[p], a1 = uw1[p];
        #pragma unroll
        for (int h=0;h<32;h++){
            unsigned w = wq[p*32+h];
            qa0[h] = fdot2(a0, w, qa0[h]);
            qa1[h] = fdot2(a1, w, qa1[h]);
        }
    }
    unsigned qpk0[16], qpk1[16];
    #pragma unroll
    for (int p=0;p<16;p++){ qpk0[p]=pkrtz(qa0[2*p],qa0[2*p+1]); qpk1[p]=pkrtz(qa1[2*p],qa1[2*p+1]); }

    // scores vs all 17 keys; k rows shared across both queries
    float sc0[JN], sc1[JN];
    #pragma unroll
    for (int kj=0;kj<JN;kj++){
        const uint4* kp = (const uint4*)(ku + ((size_t)kj*cap + sl)*16);
        uint4 a = kp[0], b = kp[1], c = kp[2], d = kp[3];
        unsigned kw[16] = {a.x,a.y,a.z,a.w,b.x,b.y,b.z,b.w,c.x,c.y,c.z,c.w,d.x,d.y,d.z,d.w};
        float s00=0.f, s01=0.f, s10=0.f, s11=0.f;
        #pragma unroll
        for (int p=0;p<16;p+=2){
            s00 = fdot2(qpk0[p],   kw[p],   s00);
            s01 = fdot2(qpk0[p+1], kw[p+1], s01);
            s10 = fdot2(qpk1[p],   kw[p],   s10);
            s11 = fdot2(qpk1[p+1], kw[p+1], s11);
        }
        sc0[kj] = s00 + s01; sc1[kj] = s10 + s11;
    }
    float m0 = sc0[0], m1 = sc1[0];
    #pragma unroll
    for (int kj=1;kj<JN;kj++){ m0 = fmaxf(m0, sc0[kj]); m1 = fmaxf(m1, sc1[kj]); }
    float e0[JN], e1[JN]; float sum0 = 0.f, sum1 = 0.f;
    #pragma unroll
    for (int kj=0;kj<JN;kj++){
        e0[kj] = __expf(sc0[kj]-m0); sum0 += e0[kj];
        e1[kj] = __expf(sc1[kj]-m1); sum1 += e1[kj];
    }
    float ri0 = 1.0f/sum0, ri1 = 1.0f/sum1;

    // o = att @ v (f16 pair accumulate); v rows shared
    unsigned o0[16], o1[16];
    #pragma unroll
    for (int p=0;p<16;p++){ o0[p]=0u; o1[p]=0u; }
    #pragma unroll
    for (int kj=0;kj<JN;kj++){
        float w0 = e0[kj]*ri0, w1 = e1[kj]*ri1;
        unsigned w20 = pkrtz(w0, w0), w21 = pkrtz(w1, w1);
        const uint4* vp = (const uint4*)(vu + ((size_t)kj*cap + sl)*16);
        uint4 a = vp[0], b = vp[1], c = vp[2], d = vp[3];
        unsigned vw[16] = {a.x,a.y,a.z,a.w,b.x,b.y,b.z,b.w,c.x,c.y,c.z,c.w,d.x,d.y,d.z,d.w};
        #pragma unroll
        for (int p=0;p<16;p++){ o0[p] = pkfma(w20, vw[p], o0[p]); o1[p] = pkfma(w21, vw[p], o1[p]); }
    }

    // d1 = leaky(o @ Wd1 + bd1)
    float t0[32], t1[32];
    #pragma unroll
    for (int h=0;h<32;h++){ float b = bd1[h]; t0[h]=b; t1[h]=b; }
    #pragma unroll
    for (int p=0;p<16;p++){
        unsigned a0 = o0[p], a1 = o1[p];
        #pragma unroll
        for (int h=0;h<32;h++){
            unsigned w = wd1[p*32+h];
            t0[h] = fdot2(a0, w, t0[h]);
            t1[h] = fdot2(a1, w, t1[h]);
        }
    }
    unsigned tp0[16], tp1[16];
    #pragma unroll
    for (int p=0;p<16;p++){
        tp0[p] = pkrtz(lrelu(t0[2*p]), lrelu(t0[2*p+1]));
        tp1[p] = pkrtz(lrelu(t1[2*p]), lrelu(t1[2*p+1]));
    }

    // d2 + residual
    float z0[32], z1[32];
    {
        const uint4* p4 = (const uint4*)(upo + ((size_t)sl*8 + q0)*16);
        uint4 a = p4[0], b = p4[1], c = p4[2], d = p4[3];
        unsigned pw[16] = {a.x,a.y,a.z,a.w,b.x,b.y,b.z,b.w,c.x,c.y,c.z,c.w,d.x,d.y,d.z,d.w};
        #pragma unroll
        for (int p=0;p<16;p++){
            h2v r = u2h(pw[p]);
            z0[2*p] = bd2[2*p] + (float)r.x; z0[2*p+1] = bd2[2*p+1] + (float)r.y;
        }
    }
    {
        const uint4* p4 = (const uint4*)(upo + ((size_t)sl*8 + q1)*16);
        uint4 a = p4[0], b = p4[1], c = p4[2], d = p4[3];
        unsigned pw[16] = {a.x,a.y,a.z,a.w,b.x,b.y,b.z,b.w,c.x,c.y,c.z,c.w,d.x,d.y,d.z,d.w};
        #pragma unroll
        for (int p=0;p<16;p++){
            h2v r = u2h(pw[p]);
            z1[2*p] = bd2[2*p] + (float)r.x; z1[2*p+1] = bd2[2*p+1] + (float)r.y;
        }
    }
    #pragma unroll
    for (int p=0;p<16;p++){
        unsigned a0 = tp0[p], a1 = tp1[p];
        #pragma unroll
        for (int h=0;h<32;h++){
            unsigned w = wd2[p*32+h];
            z0[h] = fdot2(a0, w, z0[h]);
            z1[h] = fdot2(a1, w, z1[h]);
        }
    }

    // sigmoid(z @ Ws + bs)
    float y00=0.f, y01=0.f, y10=0.f, y11=0.f;
    #pragma unroll
    for (int h=0;h<32;h+=2){
        y00 = fmaf(z0[h], Ws[h], y00); y01 = fmaf(z0[h+1], Ws[h+1], y01);
        y10 = fmaf(z1[h], Ws[h], y10); y11 = fmaf(z1[h+1], Ws[h+1], y11);
    }
    float yb = bs[0];
    float ya = y00 + y01 + yb;
    float yc = y10 + y11 + yb;
    size_t ob = ((size_t)(start + sl))*8;
    out[ob + q0] = 1.0f/(1.0f + __expf(-ya));
    out[ob + q1] = 1.0f/(1.0f + __expf(-yc));
}

extern "C" void kernel_launch(void* const* d_in, const int* in_sizes, int n_in,
                              void* d_out, int out_size, void* d_ws, size_t ws_size,
                              hipStream_t stream) {
    (void)n_in; (void)out_size;
    const float* x   = (const float*)d_in[0];
    const void*  m   = d_in[1];
    const float* pos = (const float*)d_in[2];
    const float* Wup = (const float*)d_in[3];  const float* bup = (const float*)d_in[4];
    const float* Wud = (const float*)d_in[5];  const float* bud = (const float*)d_in[6];
    const float* Wq  = (const float*)d_in[7];  const float* bq  = (const float*)d_in[8];
    const float* Wk  = (const float*)d_in[9];  const float* bk  = (const float*)d_in[10];
    const float* Wv  = (const float*)d_in[11]; const float* bv  = (const float*)d_in[12];
    const float* Wd1 = (const float*)d_in[13]; const float* bd1 = (const float*)d_in[14];
    const float* Wd2 = (const float*)d_in[15]; const float* bd2 = (const float*)d_in[16];
    const float* Ws  = (const float*)d_in[17]; const float* bs  = (const float*)d_in[18];
    float* out = (float*)d_out;
    int B = in_sizes[0] / (JN*2);

    unsigned char* wsb = (unsigned char*)d_ws;
    unsigned* ws32  = (unsigned*)wsb;                           // 64 KB header
    unsigned* bmask = (unsigned*)(wsb + HDR_BYTES);             // B u32
    size_t data_off = (HDR_BYTES + (size_t)B*4 + 255) & ~(size_t)255;
    // per-sample ws: k (17*16) + v (17*16) + uuo 128 + upo 128 = 800 u32 = 3200 B
    long cap = 0;
    if (ws_size > data_off) cap = (long)((ws_size - data_off) / 3200);
    cap = (cap/64)*64;
    if (cap <= 0) return;
    if (cap > B) cap = (long)B;
    unsigned* ku  = (unsigned*)(wsb + data_off);
    unsigned* vu  = ku  + (size_t)cap*272;
    unsigned* uuo = ku  + (size_t)cap*544;
    unsigned* upo = ku  + (size_t)cap*672;

    prep_kernel<<<(B+255)/256, 256, 0, stream>>>(m, pos, Wup, Wud, bud, Wq, bq,
                                                 Wk, Wv, Wd1, Wd2, ws32, bmask, B);
    for (long start = 0; start < B; start += cap){
        int n = (int)((B - start < cap) ? (B - start) : cap);
        dim3 g1((n+255)/256, JN);
        pass1_kernel<<<g1, 256, 0, stream>>>(x, bmask, ws32, bup, bk, bv,
                                             ku, vu, uuo, upo, (int)start, n, cap);
        pass2_kernel<<<(n*4 + 255)/256, 256, 0, stream>>>(ku, vu, uuo, upo, ws32,
                                                          bd1, bd2, Ws, bs,
                                                          out, (int)start, n, cap);
    }
}

// Round 8
// 117.436 us; speedup vs baseline: 1.7945x; 1.3460x over previous
//
#include <hip/hip_runtime.h>
#include <hip/hip_fp16.h>

#define JN 17

typedef __fp16 h2v __attribute__((ext_vector_type(2)));
typedef _Float16 f16x8 __attribute__((ext_vector_type(8)));
typedef float f32x4 __attribute__((ext_vector_type(4)));

__device__ __forceinline__ float lrelu(float x){ return fmaxf(x, 0.01f*x); }
__device__ __forceinline__ unsigned h2u(h2v h){ unsigned u; __builtin_memcpy(&u, &h, 4); return u; }
__device__ __forceinline__ h2v u2h(unsigned u){ h2v h; __builtin_memcpy(&h, &u, 4); return h; }
__device__ __forceinline__ unsigned pkrtz(float a, float b){ return h2u(__builtin_amdgcn_cvt_pkrtz(a,b)); }
__device__ __forceinline__ float fdot2(unsigned a, unsigned b, float c){
    return __builtin_amdgcn_fdot2(u2h(a), u2h(b), c, false);
}
__device__ __forceinline__ unsigned pkfma(unsigned a, unsigned b, unsigned c){
    h2v r = u2h(a)*u2h(b) + u2h(c);
    return h2u(r);
}
__device__ __forceinline__ f16x8 u4h8(uint4 u){ union{uint4 u; f16x8 h;} c; c.u=u; return c.h; }

// ws header layout (u32 units), first 65536 bytes
#define OFF_PP    0        // 544 f32 : bud + positions @ Wud[32:64]
#define OFF_BQS   544      // 32 f32  : bq * isq
#define OFF_WQI   576      // 512     : Wq*isq pairs, rows (p, p+16)  [interleaved]
#define OFF_WD1I  1088     // 512     : Wd1 pairs, rows (p, p+16)     [interleaved]
#define OFF_WD2   1600     // 512     : Wd2 pairs, rows (2p, 2p+1)    [original]
#define OFF_FUD   2112     // 512     : Wud[0:32] B-fragments (2 tiles x 64 lanes x 4 dw)
#define OFF_FK    2624     // 512
#define OFF_FV    3136     // 512
#define OFF_TUP   3648     // 544     : Wup rows 32,33 pairs, [j][t][c]
#define OFF_FUP   4192     // 8704    : Wup[0:32] B-fragments per j
#define HDR_BYTES 65536

// ---------------- prep ------------------------------------------------------
__global__ __launch_bounds__(256,1)
void prep_kernel(const void* __restrict__ mraw, const float* __restrict__ pos,
                 const float* __restrict__ Wup,
                 const float* __restrict__ Wud, const float* __restrict__ bud,
                 const float* __restrict__ Wq,  const float* __restrict__ bq,
                 const float* __restrict__ Wk,  const float* __restrict__ Wv,
                 const float* __restrict__ Wd1, const float* __restrict__ Wd2,
                 unsigned* __restrict__ ws32, unsigned* __restrict__ bmask, int B)
{
    int g = blockIdx.x*256 + threadIdx.x;
    const float isq = 0.17677669529663687f;

    // mask mode detection (encodings mutually exclusive given 9-of-17 True)
    const unsigned* mw = (const unsigned*)mraw;
    bool f3f=false, nz=false;
    #pragma unroll
    for (int i=0;i<17;i++){
        unsigned w = mw[i];
        if ((w>>24) == 0x3Fu) f3f = true;
        if (w & 0xFFFFFF00u)  nz  = true;
    }
    int mode = f3f ? 2 : (nz ? 1 : 0);
    if (g < B){
        unsigned bm = 0; size_t base = (size_t)g*JN;
        if (mode == 0){
            const int* mi = (const int*)mraw;
            #pragma unroll
            for (int j=0;j<JN;j++) if (mi[base+j] != 0) bm |= (1u<<j);
        } else if (mode == 1){
            const unsigned char* mb = (const unsigned char*)mraw;
            #pragma unroll
            for (int j=0;j<JN;j++) if (mb[base+j] != 0) bm |= (1u<<j);
        } else {
            const float* mf = (const float*)mraw;
            #pragma unroll
            for (int j=0;j<JN;j++) if (mf[base+j] != 0.f) bm |= (1u<<j);
        }
        bmask[g] = bm;
    }
    if (g < 544){
        int j = g >> 5, h = g & 31;
        float acc = bud[h];
        #pragma unroll
        for (int c=0;c<32;c++) acc = fmaf(pos[j*32+c], Wud[(32+c)*32 + h], acc);
        ((float*)ws32)[OFF_PP + g] = acc;
        // TUP: pairs of Wup rows 32,33; index g = j*32 + t*16 + c
        int t = (g >> 4) & 1, c = g & 15;
        int col = j*32 + t*16 + c;
        ws32[OFF_TUP + g] = pkrtz(Wup[32*544 + col], Wup[33*544 + col]);
    }
    if (g < 32) ((float*)ws32)[OFF_BQS + g] = bq[g]*isq;
    if (g < 512){
        // B-fragments (A/B layout: col = lane&15, k = (lane>>4)*8 + i, dword i2 = k pair)
        int t = g >> 8, r = g & 255, lane = r >> 2, i2 = r & 3;
        int k0 = (lane>>4)*8 + 2*i2, c = (lane&15) + 16*t;
        ws32[OFF_FUD + g] = pkrtz(Wud[k0*32 + c], Wud[(k0+1)*32 + c]);
        ws32[OFF_FK  + g] = pkrtz(Wk [k0*32 + c], Wk [(k0+1)*32 + c]);
        ws32[OFF_FV  + g] = pkrtz(Wv [k0*32 + c], Wv [(k0+1)*32 + c]);
        // pass2 tables
        int p = g >> 5, h = g & 31;
        ws32[OFF_WQI  + g] = pkrtz(Wq [p*32+h]*isq,   Wq [(p+16)*32+h]*isq);
        ws32[OFF_WD1I + g] = pkrtz(Wd1[p*32+h],       Wd1[(p+16)*32+h]);
        ws32[OFF_WD2  + g] = pkrtz(Wd2[(2*p)*32+h],   Wd2[(2*p+1)*32+h]);
    }
    if (g < 8704){
        int j = g >> 9, r = g & 511, t = r >> 8, rr = r & 255, lane = rr >> 2, i2 = rr & 3;
        int k0 = (lane>>4)*8 + 2*i2;
        int col = j*32 + (lane&15) + 16*t;
        ws32[OFF_FUP + g] = pkrtz(Wup[k0*544 + col], Wup[(k0+1)*544 + col]);
    }
}

// ---------------- pass 1 (MFMA): wave = 16 samples x one j -------------------
__global__ __launch_bounds__(256)
void pass1_kernel(const float* __restrict__ x, const unsigned* __restrict__ bmask,
                  const unsigned* __restrict__ ws32,
                  const float* __restrict__ bup,
                  const float* __restrict__ bk, const float* __restrict__ bv,
                  unsigned* __restrict__ ku, unsigned* __restrict__ vu,
                  unsigned* __restrict__ uuo, unsigned* __restrict__ upo,
                  int start, int n, long cap)
{
    __shared__ float als[4][16*34];   // per-wave repack tile, row stride 34 (bank spread)
    const int wid = threadIdx.x >> 6, wl = threadIdx.x & 63;
    const int sblk = blockIdx.x*64 + wid*16;       // chunk-local sample base of this wave
    if (sblk >= n) return;
    const int j = blockIdx.y;
    const int srow = wl & 15;        // A-row (sample) / C-col index
    const int g4   = wl >> 4;        // k-block / C row-group
    const int s0g  = start + sblk;
    const int smax = start + n - 1;

    // ---- A-frag of x: sample srow, k = g4*8 .. +7 ----
    f16x8 ax;
    {
        int sA = s0g + srow; if (sA > smax) sA = smax;
        const float* xr = x + (size_t)sA*34 + g4*8;
        float2 a0 = *(const float2*)(xr);
        float2 a1 = *(const float2*)(xr+2);
        float2 a2 = *(const float2*)(xr+4);
        float2 a3 = *(const float2*)(xr+6);
        uint4 u; u.x = pkrtz(a0.x,a0.y); u.y = pkrtz(a1.x,a1.y);
        u.z = pkrtz(a2.x,a2.y); u.w = pkrtz(a3.x,a3.y);
        ax = u4h8(u);
    }

    // ---- B-fragments (L2-hot tables) ----
    const uint4* wsu4 = (const uint4*)ws32;
    f16x8 fup0 = u4h8(wsu4[OFF_FUP/4 + j*128 +       wl]);
    f16x8 fup1 = u4h8(wsu4[OFF_FUP/4 + j*128 + 64 +  wl]);
    f16x8 fud0 = u4h8(wsu4[OFF_FUD/4 +       wl]);
    f16x8 fud1 = u4h8(wsu4[OFF_FUD/4 + 64 +  wl]);
    f16x8 fk0  = u4h8(wsu4[OFF_FK/4  +       wl]);
    f16x8 fk1  = u4h8(wsu4[OFF_FK/4  + 64 +  wl]);
    f16x8 fv0  = u4h8(wsu4[OFF_FV/4  +       wl]);
    f16x8 fv1  = u4h8(wsu4[OFF_FV/4  + 64 +  wl]);
    unsigned tup0 = ws32[OFF_TUP + j*32 + srow];
    unsigned tup1 = ws32[OFF_TUP + j*32 + 16 + srow];

    const float* ppf = (const float*)ws32;
    float bupv0 = bup[j*32 + srow],        bupv1 = bup[j*32 + 16 + srow];
    float ppv0  = ppf[OFF_PP + j*32 + srow], ppv1 = ppf[OFF_PP + j*32 + 16 + srow];
    float bkv0  = bk[srow], bkv1 = bk[16 + srow];
    float bvv0  = bv[srow], bvv1 = bv[16 + srow];

    // per-C-row (r = g4*4+reg) bmask + x tail pair (k=32,33)
    unsigned bmr[4]; float2 xt[4];
    #pragma unroll
    for (int reg=0; reg<4; reg++){
        int sr = s0g + g4*4 + reg; if (sr > smax) sr = smax;
        bmr[reg] = bmask[sr];
        xt[reg]  = *(const float2*)(x + (size_t)sr*34 + 32);
    }

    // ---- up = leaky(x @ Wup_j + bup_j) ----
    f32x4 up0 = {bupv0,bupv0,bupv0,bupv0};
    f32x4 up1 = {bupv1,bupv1,bupv1,bupv1};
    up0 = __builtin_amdgcn_mfma_f32_16x16x32_f16(ax, fup0, up0, 0, 0, 0);
    up1 = __builtin_amdgcn_mfma_f32_16x16x32_f16(ax, fup1, up1, 0, 0, 0);
    #pragma unroll
    for (int reg=0; reg<4; reg++){
        unsigned xp = pkrtz(xt[reg].x, xt[reg].y);
        up0[reg] = fdot2(xp, tup0, up0[reg]);
        up1[reg] = fdot2(xp, tup1, up1[reg]);
    }
    #pragma unroll
    for (int reg=0; reg<4; reg++){ up0[reg] = lrelu(up0[reg]); up1[reg] = lrelu(up1[reg]); }

    // occluded residual rows (interleaved pairs (h, h+16) per dword)
    #pragma unroll
    for (int reg=0; reg<4; reg++){
        int r = g4*4 + reg;
        unsigned bm = bmr[reg];
        if ((sblk + r < n) && !((bm>>j)&1u)){
            int rk = __popc((~bm) & ((1u<<j)-1u));
            upo[((size_t)(sblk+r)*8 + rk)*16 + srow] = pkrtz(up0[reg], up1[reg]);
        }
    }

    // repack up (C-layout) -> LDS -> A-frag
    #pragma unroll
    for (int reg=0; reg<4; reg++){
        int r = g4*4 + reg;
        als[wid][r*34 + srow]      = up0[reg];
        als[wid][r*34 + 16 + srow] = up1[reg];
    }
    asm volatile("s_waitcnt lgkmcnt(0)" ::: "memory");
    __builtin_amdgcn_sched_barrier(0);
    f16x8 aup;
    {
        const float* rp = &als[wid][srow*34 + g4*8];
        float2 a0 = *(const float2*)(rp);
        float2 a1 = *(const float2*)(rp+2);
        float2 a2 = *(const float2*)(rp+4);
        float2 a3 = *(const float2*)(rp+6);
        uint4 u; u.x = pkrtz(a0.x,a0.y); u.y = pkrtz(a1.x,a1.y);
        u.z = pkrtz(a2.x,a2.y); u.w = pkrtz(a3.x,a3.y);
        aup = u4h8(u);
    }

    // ---- uu = leaky(pp_j + up @ Wud0) ----
    f32x4 uu0 = {ppv0,ppv0,ppv0,ppv0};
    f32x4 uu1 = {ppv1,ppv1,ppv1,ppv1};
    uu0 = __builtin_amdgcn_mfma_f32_16x16x32_f16(aup, fud0, uu0, 0, 0, 0);
    uu1 = __builtin_amdgcn_mfma_f32_16x16x32_f16(aup, fud1, uu1, 0, 0, 0);
    #pragma unroll
    for (int reg=0; reg<4; reg++){ uu0[reg] = lrelu(uu0[reg]); uu1[reg] = lrelu(uu1[reg]); }

    #pragma unroll
    for (int reg=0; reg<4; reg++){
        int r = g4*4 + reg;
        unsigned bm = bmr[reg];
        if ((sblk + r < n) && !((bm>>j)&1u)){
            int rk = __popc((~bm) & ((1u<<j)-1u));
            uuo[((size_t)(sblk+r)*8 + rk)*16 + srow] = pkrtz(uu0[reg], uu1[reg]);
        }
    }

    // repack uu -> A-frag (overwrite als; wave-synchronous, in-order LDS)
    #pragma unroll
    for (int reg=0; reg<4; reg++){
        int r = g4*4 + reg;
        als[wid][r*34 + srow]      = uu0[reg];
        als[wid][r*34 + 16 + srow] = uu1[reg];
    }
    asm volatile("s_waitcnt lgkmcnt(0)" ::: "memory");
    __builtin_amdgcn_sched_barrier(0);
    f16x8 auu;
    {
        const float* rp = &als[wid][srow*34 + g4*8];
        float2 a0 = *(const float2*)(rp);
        float2 a1 = *(const float2*)(rp+2);
        float2 a2 = *(const float2*)(rp+4);
        float2 a3 = *(const float2*)(rp+6);
        uint4 u; u.x = pkrtz(a0.x,a0.y); u.y = pkrtz(a1.x,a1.y);
        u.z = pkrtz(a2.x,a2.y); u.w = pkrtz(a3.x,a3.y);
        auu = u4h8(u);
    }

    // ---- k, v ----
    f32x4 k0 = {bkv0,bkv0,bkv0,bkv0}, k1 = {bkv1,bkv1,bkv1,bkv1};
    f32x4 v0 = {bvv0,bvv0,bvv0,bvv0}, v1 = {bvv1,bvv1,bvv1,bvv1};
    k0 = __builtin_amdgcn_mfma_f32_16x16x32_f16(auu, fk0, k0, 0, 0, 0);
    k1 = __builtin_amdgcn_mfma_f32_16x16x32_f16(auu, fk1, k1, 0, 0, 0);
    v0 = __builtin_amdgcn_mfma_f32_16x16x32_f16(auu, fv0, v0, 0, 0, 0);
    v1 = __builtin_amdgcn_mfma_f32_16x16x32_f16(auu, fv1, v1, 0, 0, 0);

    // stores: interleaved pairs (h, h+16) per dword; row = 16 dwords = 64 B
    #pragma unroll
    for (int reg=0; reg<4; reg++){
        int r = g4*4 + reg;
        if (sblk + r < n){
            size_t base = ((size_t)j*cap + (sblk+r))*16 + srow;
            ku[base] = pkrtz(k0[reg], k1[reg]);
            vu[base] = pkrtz(v0[reg], v1[reg]);
        }
    }
}

// ---------------- pass 2: one lane per (sample, 2 queries) -------------------
__global__ __launch_bounds__(256,4)
void pass2_kernel(const unsigned* __restrict__ ku, const unsigned* __restrict__ vu,
                  const unsigned* __restrict__ uuo, const unsigned* __restrict__ upo,
                  const unsigned* __restrict__ ws32,
                  const float* __restrict__ bd1, const float* __restrict__ bd2,
                  const float* __restrict__ Ws, const float* __restrict__ bs,
                  float* __restrict__ out, int start, int n, long cap)
{
    int g = blockIdx.x*256 + threadIdx.x;
    if (g >= n*4) return;
    int sl = g >> 2, qp = g & 3;
    int q0 = qp, q1 = qp + 4;

    const unsigned* wqI  = ws32 + OFF_WQI;
    const unsigned* wd1I = ws32 + OFF_WD1I;
    const unsigned* wd2  = ws32 + OFF_WD2;
    const float*    bqs  = (const float*)ws32 + OFF_BQS;

    // uu rows (interleaved pairs (k, k+16) per dword)
    unsigned uw0[16], uw1[16];
    {
        const uint4* p4 = (const uint4*)(uuo + ((size_t)sl*8 + q0)*16);
        uint4 a = p4[0], b = p4[1], c = p4[2], d = p4[3];
        uw0[0]=a.x; uw0[1]=a.y; uw0[2]=a.z; uw0[3]=a.w;
        uw0[4]=b.x; uw0[5]=b.y; uw0[6]=b.z; uw0[7]=b.w;
        uw0[8]=c.x; uw0[9]=c.y; uw0[10]=c.z; uw0[11]=c.w;
        uw0[12]=d.x; uw0[13]=d.y; uw0[14]=d.z; uw0[15]=d.w;
    }
    {
        const uint4* p4 = (const uint4*)(uuo + ((size_t)sl*8 + q1)*16);
        uint4 a = p4[0], b = p4[1], c = p4[2], d = p4[3];
        uw1[0]=a.x; uw1[1]=a.y; uw1[2]=a.z; uw1[3]=a.w;
        uw1[4]=b.x; uw1[5]=b.y; uw1[6]=b.z; uw1[7]=b.w;
        uw1[8]=c.x; uw1[9]=c.y; uw1[10]=c.z; uw1[11]=c.w;
        uw1[12]=d.x; uw1[13]=d.y; uw1[14]=d.z; uw1[15]=d.w;
    }

    float qa0[32], qa1[32];
    #pragma unroll
    for (int h=0;h<32;h++){ float b = bqs[h]; qa0[h]=b; qa1[h]=b; }
    #pragma unroll
    for (int p=0;p<16;p++){
        unsigned a0 = uw0[p], a1 = uw1[p];
        #pragma unroll
        for (int h=0;h<32;h++){
            unsigned w = wqI[p*32+h];
            qa0[h] = fdot2(a0, w, qa0[h]);
            qa1[h] = fdot2(a1, w, qa1[h]);
        }
    }
    // pack q interleaved (h, h+16) to match k-row dword order
    unsigned qpk0[16], qpk1[16];
    #pragma unroll
    for (int p=0;p<16;p++){ qpk0[p]=pkrtz(qa0[p],qa0[p+16]); qpk1[p]=pkrtz(qa1[p],qa1[p+16]); }

    // scores vs all 17 keys
    float sc0[JN], sc1[JN];
    #pragma unroll
    for (int kj=0;kj<JN;kj++){
        const uint4* kp = (const uint4*)(ku + ((size_t)kj*cap + sl)*16);
        uint4 a = kp[0], b = kp[1], c = kp[2], d = kp[3];
        unsigned kw[16] = {a.x,a.y,a.z,a.w,b.x,b.y,b.z,b.w,c.x,c.y,c.z,c.w,d.x,d.y,d.z,d.w};
        float s00=0.f, s01=0.f, s10=0.f, s11=0.f;
        #pragma unroll
        for (int p=0;p<16;p+=2){
            s00 = fdot2(qpk0[p],   kw[p],   s00);
            s01 = fdot2(qpk0[p+1], kw[p+1], s01);
            s10 = fdot2(qpk1[p],   kw[p],   s10);
            s11 = fdot2(qpk1[p+1], kw[p+1], s11);
        }
        sc0[kj] = s00 + s01; sc1[kj] = s10 + s11;
    }
    float m0 = sc0[0], m1 = sc1[0];
    #pragma unroll
    for (int kj=1;kj<JN;kj++){ m0 = fmaxf(m0, sc0[kj]); m1 = fmaxf(m1, sc1[kj]); }
    float e0[JN], e1[JN]; float sum0 = 0.f, sum1 = 0.f;
    #pragma unroll
    for (int kj=0;kj<JN;kj++){
        e0[kj] = __expf(sc0[kj]-m0); sum0 += e0[kj];
        e1[kj] = __expf(sc1[kj]-m1); sum1 += e1[kj];
    }
    float ri0 = 1.0f/sum0, ri1 = 1.0f/sum1;

    // o = att @ v (f16 pair accumulate, interleaved pair order)
    unsigned o0[16], o1[16];
    #pragma unroll
    for (int p=0;p<16;p++){ o0[p]=0u; o1[p]=0u; }
    #pragma unroll
    for (int kj=0;kj<JN;kj++){
        float w0 = e0[kj]*ri0, w1 = e1[kj]*ri1;
        unsigned w20 = pkrtz(w0, w0), w21 = pkrtz(w1, w1);
        const uint4* vp = (const uint4*)(vu + ((size_t)kj*cap + sl)*16);
        uint4 a = vp[0], b = vp[1], c = vp[2], d = vp[3];
        unsigned vw[16] = {a.x,a.y,a.z,a.w,b.x,b.y,b.z,b.w,c.x,c.y,c.z,c.w,d.x,d.y,d.z,d.w};
        #pragma unroll
        for (int p=0;p<16;p++){ o0[p] = pkfma(w20, vw[p], o0[p]); o1[p] = pkfma(w21, vw[p], o1[p]); }
    }

    // d1 = leaky(o @ Wd1 + bd1) (interleaved weight table matches o order)
    float t0[32], t1[32];
    #pragma unroll
    for (int h=0;h<32;h++){ float b = bd1[h]; t0[h]=b; t1[h]=b; }
    #pragma unroll
    for (int p=0;p<16;p++){
        unsigned a0 = o0[p], a1 = o1[p];
        #pragma unroll
        for (int h=0;h<32;h++){
            unsigned w = wd1I[p*32+h];
            t0[h] = fdot2(a0, w, t0[h]);
            t1[h] = fdot2(a1, w, t1[h]);
        }
    }
    unsigned tp0[16], tp1[16];
    #pragma unroll
    for (int p=0;p<16;p++){
        tp0[p] = pkrtz(lrelu(t0[2*p]), lrelu(t0[2*p+1]));
        tp1[p] = pkrtz(lrelu(t1[2*p]), lrelu(t1[2*p+1]));
    }

    // d2 + residual (upo rows interleaved)
    float z0[32], z1[32];
    {
        const uint4* p4 = (const uint4*)(upo + ((size_t)sl*8 + q0)*16);
        uint4 a = p4[0], b = p4[1], c = p4[2], d = p4[3];
        unsigned pw[16] = {a.x,a.y,a.z,a.w,b.x,b.y,b.z,b.w,c.x,c.y,c.z,c.w,d.x,d.y,d.z,d.w};
        #pragma unroll
        for (int p=0;p<16;p++){
            h2v r = u2h(pw[p]);
            z0[p] = bd2[p] + (float)r.x; z0[p+16] = bd2[p+16] + (float)r.y;
        }
    }
    {
        const uint4* p4 = (const uint4*)(upo + ((size_t)sl*8 + q1)*16);
        uint4 a = p4[0], b = p4[1], c = p4[2], d = p4[3];
        unsigned pw[16] = {a.x,a.y,a.z,a.w,b.x,b.y,b.z,b.w,c.x,c.y,c.z,c.w,d.x,d.y,d.z,d.w};
        #pragma unroll
        for (int p=0;p<16;p++){
            h2v r = u2h(pw[p]);
            z1[p] = bd2[p] + (float)r.x; z1[p+16] = bd2[p+16] + (float)r.y;
        }
    }
    #pragma unroll
    for (int p=0;p<16;p++){
        unsigned a0 = tp0[p], a1 = tp1[p];
        #pragma unroll
        for (int h=0;h<32;h++){
            unsigned w = wd2[p*32+h];
            z0[h] = fdot2(a0, w, z0[h]);
            z1[h] = fdot2(a1, w, z1[h]);
        }
    }

    // sigmoid(z @ Ws + bs)
    float y00=0.f, y01=0.f, y10=0.f, y11=0.f;
    #pragma unroll
    for (int h=0;h<32;h+=2){
        y00 = fmaf(z0[h], Ws[h], y00); y01 = fmaf(z0[h+1], Ws[h+1], y01);
        y10 = fmaf(z1[h], Ws[h], y10); y11 = fmaf(z1[h+1], Ws[h+1], y11);
    }
    float yb = bs[0];
    float ya = y00 + y01 + yb;
    float yc = y10 + y11 + yb;
    size_t ob = ((size_t)(start + sl))*8;
    out[ob + q0] = 1.0f/(1.0f + __expf(-ya));
    out[ob + q1] = 1.0f/(1.0f + __expf(-yc));
}

extern "C" void kernel_launch(void* const* d_in, const int* in_sizes, int n_in,
                              void* d_out, int out_size, void* d_ws, size_t ws_size,
                              hipStream_t stream) {
    (void)n_in; (void)out_size;
    const float* x   = (const float*)d_in[0];
    const void*  m   = d_in[1];
    const float* pos = (const float*)d_in[2];
    const float* Wup = (const float*)d_in[3];  const float* bup = (const float*)d_in[4];
    const float* Wud = (const float*)d_in[5];  const float* bud = (const float*)d_in[6];
    const float* Wq  = (const float*)d_in[7];  const float* bq  = (const float*)d_in[8];
    const float* Wk  = (const float*)d_in[9];  const float* bk  = (const float*)d_in[10];
    const float* Wv  = (const float*)d_in[11]; const float* bv  = (const float*)d_in[12];
    const float* Wd1 = (const float*)d_in[13]; const float* bd1 = (const float*)d_in[14];
    const float* Wd2 = (const float*)d_in[15]; const float* bd2 = (const float*)d_in[16];
    const float* Ws  = (const float*)d_in[17]; const float* bs  = (const float*)d_in[18];
    float* out = (float*)d_out;
    int B = in_sizes[0] / (JN*2);

    unsigned char* wsb = (unsigned char*)d_ws;
    unsigned* ws32  = (unsigned*)wsb;                           // 64 KB header
    unsigned* bmask = (unsigned*)(wsb + HDR_BYTES);             // B u32
    size_t data_off = (HDR_BYTES + (size_t)B*4 + 255) & ~(size_t)255;
    // per-sample ws: k 272 + v 272 + uuo 128 + upo 128 = 800 u32 = 3200 B
    long cap = 0;
    if (ws_size > data_off) cap = (long)((ws_size - data_off) / 3200);
    cap = (cap/64)*64;
    if (cap <= 0) return;
    if (cap > B) cap = (long)B;
    unsigned* ku  = (unsigned*)(wsb + data_off);
    unsigned* vu  = ku  + (size_t)cap*272;
    unsigned* uuo = ku  + (size_t)cap*544;
    unsigned* upo = ku  + (size_t)cap*672;

    prep_kernel<<<(B+255)/256, 256, 0, stream>>>(m, pos, Wup, Wud, bud, Wq, bq,
                                                 Wk, Wv, Wd1, Wd2, ws32, bmask, B);
    for (long start = 0; start < B; start += cap){
        int n = (int)((B - start < cap) ? (B - start) : cap);
        dim3 g1((n+63)/64, JN);
        pass1_kernel<<<g1, 256, 0, stream>>>(x, bmask, ws32, bup, bk, bv,
                                             ku, vu, uuo, upo, (int)start, n, cap);
        pass2_kernel<<<(n*4 + 255)/256, 256, 0, stream>>>(ku, vu, uuo, upo, ws32,
                                                          bd1, bd2, Ws, bs,
                                                          out, (int)start, n, cap);
    }
}